// Round 1
// baseline (6561.698 us; speedup 1.0000x reference)
//
#include <hip/hip_runtime.h>
#include <cstddef>
#include <cstdint>

// ---------------------------------------------------------------------------
// LogicRecursiveNN — Round 1: correctness-first fp32 implementation.
// Structure: fused-gather level-1 GEMM, 6 tree levels (two2one), one2one,
// feat concat, 3-layer head, final dot+sigmoid.
// Generic tiled GEMM: BM=BN=64, BK=16, 256 thr, 4x4 per-thread micro-tile.
// All M/N/K used are multiples of the tile sizes (no edge handling needed).
// Workspace: bufA(64MB) bufB(64MB) H(32MB) + head scratch ~= 173 MB.
// ---------------------------------------------------------------------------

#define BM 64
#define BN 64
#define BKK 16

// act: 0 = none, 1 = relu, 2 = tanh
template <int GATHER>
__global__ __launch_bounds__(256) void gemm_bias_act(
    const float* __restrict__ A, const float* __restrict__ W,
    const float* __restrict__ bias, float* __restrict__ C, int M, int N, int K,
    int act, const int* __restrict__ lidx, const float* __restrict__ emb) {
  __shared__ float As[BKK][BM + 4];
  __shared__ float Ws[BKK][BN];
  const int tid = threadIdx.x;
  const int m0 = blockIdx.y * BM;
  const int n0 = blockIdx.x * BN;
  const int tm = (tid >> 4) << 2;  // 0..60
  const int tn = (tid & 15) << 2;  // 0..60

  const int lm = tid >> 2;        // A-load row within tile (0..63)
  const int lk = (tid & 3) << 2;  // A-load k offset (0,4,8,12)
  const int wk = tid >> 4;        // W-load k (0..15)
  const int wn = (tid & 15) << 2; // W-load n offset

  float acc[4][4] = {};

  for (int k0 = 0; k0 < K; k0 += BKK) {
    float4 av;
    if (GATHER) {
      // Level-1 A is ent_emb[leaf_idx] fused: row r, col k ->
      // entity = lidx[2*r + (k>>9)], elem = k & 511.  (K == 1024 here.)
      int gk = k0 + lk;
      int ent = lidx[((m0 + lm) << 1) + (gk >> 9)];
      av = *(const float4*)(emb + ((size_t)ent << 9) + (gk & 511));
    } else {
      av = *(const float4*)(A + (size_t)(m0 + lm) * K + k0 + lk);
    }
    As[lk + 0][lm] = av.x;
    As[lk + 1][lm] = av.y;
    As[lk + 2][lm] = av.z;
    As[lk + 3][lm] = av.w;

    *(float4*)&Ws[wk][wn] =
        *(const float4*)(W + (size_t)(k0 + wk) * N + n0 + wn);

    __syncthreads();
#pragma unroll
    for (int k = 0; k < BKK; ++k) {
      float4 a = *(const float4*)&As[k][tm];
      float4 w = *(const float4*)&Ws[k][tn];
      acc[0][0] += a.x * w.x; acc[0][1] += a.x * w.y;
      acc[0][2] += a.x * w.z; acc[0][3] += a.x * w.w;
      acc[1][0] += a.y * w.x; acc[1][1] += a.y * w.y;
      acc[1][2] += a.y * w.z; acc[1][3] += a.y * w.w;
      acc[2][0] += a.z * w.x; acc[2][1] += a.z * w.y;
      acc[2][2] += a.z * w.z; acc[2][3] += a.z * w.w;
      acc[3][0] += a.w * w.x; acc[3][1] += a.w * w.y;
      acc[3][2] += a.w * w.z; acc[3][3] += a.w * w.w;
    }
    __syncthreads();
  }

#pragma unroll
  for (int i = 0; i < 4; ++i) {
#pragma unroll
    for (int j = 0; j < 4; ++j) {
      float c = acc[i][j] + bias[n0 + tn + j];
      if (act == 1)
        c = fmaxf(c, 0.0f);
      else if (act == 2)
        c = tanhf(c);
      C[(size_t)(m0 + tm + i) * N + n0 + tn + j] = c;
    }
  }
}

// feat[b, 0:512] = th_emb; feat[b, 512:1536] = root2[b*1024 : b*1024+1024]
__global__ void build_feat(const float* __restrict__ th,
                           const float* __restrict__ root2,
                           float* __restrict__ feat) {
  int idx = blockIdx.x * 256 + threadIdx.x;  // 512*1536 total
  int b = idx / 1536;
  int c = idx - b * 1536;
  feat[idx] = (c < 512) ? th[c] : root2[(size_t)b * 1024 + (c - 512)];
}

// out[row] = sigmoid(dot(z3[row, 0:128], h4) + hb4)
__global__ void head_final(const float* __restrict__ z3,
                           const float* __restrict__ h4,
                           const float* __restrict__ hb4,
                           float* __restrict__ out) {
  int row = blockIdx.x;
  int t = threadIdx.x;  // 64 threads
  float v = z3[(size_t)row * 128 + t] * h4[t] +
            z3[(size_t)row * 128 + 64 + t] * h4[64 + t];
#pragma unroll
  for (int off = 32; off; off >>= 1) v += __shfl_down(v, off);
  if (t == 0) out[row] = 1.0f / (1.0f + expf(-(v + hb4[0])));
}

extern "C" void kernel_launch(void* const* d_in, const int* in_sizes, int n_in,
                              void* d_out, int out_size, void* d_ws,
                              size_t ws_size, hipStream_t stream) {
  const int* leaf_idx = (const int*)d_in[0];
  const float* ent_emb = (const float*)d_in[1];
  const float* th_emb = (const float*)d_in[2];
  const float* w1 = (const float*)d_in[3];
  const float* b1 = (const float*)d_in[4];
  const float* w2 = (const float*)d_in[5];
  const float* b2 = (const float*)d_in[6];
  const float* o1 = (const float*)d_in[7];
  const float* ob1 = (const float*)d_in[8];
  const float* o2 = (const float*)d_in[9];
  const float* ob2 = (const float*)d_in[10];
  const float* h1 = (const float*)d_in[11];
  const float* hb1 = (const float*)d_in[12];
  const float* h2 = (const float*)d_in[13];
  const float* hb2 = (const float*)d_in[14];
  const float* h3 = (const float*)d_in[15];
  const float* hb3 = (const float*)d_in[16];
  const float* h4 = (const float*)d_in[17];
  const float* hb4 = (const float*)d_in[18];
  float* out = (float*)d_out;

  float* ws = (float*)d_ws;
  float* bufA = ws;                              // 32768*512 = 64 MB
  float* bufB = bufA + (size_t)32768 * 512;      // 64 MB
  float* Hbuf = bufB + (size_t)32768 * 512;      // 4096*2048 = 32 MB
  float* feat = Hbuf + (size_t)4096 * 2048;      // 512*1536
  float* z1 = feat + (size_t)512 * 1536;         // 512*512
  float* z2 = z1 + (size_t)512 * 512;            // 512*256
  float* z3 = z2 + (size_t)512 * 256;            // 512*128

  const int CHUNK = 4096;
  float* bufs[2] = {bufA, bufB};
  int cur = 0;
  const float* in = nullptr;
  int pairs = 32;

  for (int level = 0; level < 6; ++level) {
    int M = 1024 * pairs;  // B * N_TREES * pairs
    float* outb = bufs[cur];
    for (int r0 = 0; r0 < M; r0 += CHUNK) {
      int rows = (M - r0 < CHUNK) ? (M - r0) : CHUNK;
      dim3 g1(2048 / BN, rows / BM);
      if (level == 0) {
        gemm_bias_act<1><<<g1, 256, 0, stream>>>(
            nullptr, w1, b1, Hbuf, rows, 2048, 1024, 1,
            leaf_idx + (size_t)2 * r0, ent_emb);
      } else {
        gemm_bias_act<0><<<g1, 256, 0, stream>>>(
            in + (size_t)r0 * 1024, w1, b1, Hbuf, rows, 2048, 1024, 1, nullptr,
            nullptr);
      }
      dim3 g2(512 / BN, rows / BM);
      gemm_bias_act<0><<<g2, 256, 0, stream>>>(
          Hbuf, w2, b2, outb + (size_t)r0 * 512, rows, 512, 2048, 1, nullptr,
          nullptr);
    }
    in = outb;  // next level reads this buffer as [M/2, 1024]
    cur ^= 1;
    pairs >>= 1;
  }

  // one2one: root [1024,512] -> relu(root@o1+ob1) [1024,2048] -> tanh(..@o2+ob2)
  {
    dim3 g1(2048 / BN, 1024 / BM);
    gemm_bias_act<0><<<g1, 256, 0, stream>>>(in, o1, ob1, Hbuf, 1024, 2048,
                                             512, 1, nullptr, nullptr);
    float* root2 = bufs[cur];
    dim3 g2(512 / BN, 1024 / BM);
    gemm_bias_act<0><<<g2, 256, 0, stream>>>(Hbuf, o2, ob2, root2, 1024, 512,
                                             2048, 2, nullptr, nullptr);
    in = root2;
  }

  // feat concat
  build_feat<<<(512 * 1536) / 256, 256, 0, stream>>>(th_emb, in, feat);

  // head
  gemm_bias_act<0><<<dim3(512 / BN, 512 / BM), 256, 0, stream>>>(
      feat, h1, hb1, z1, 512, 512, 1536, 1, nullptr, nullptr);
  gemm_bias_act<0><<<dim3(256 / BN, 512 / BM), 256, 0, stream>>>(
      z1, h2, hb2, z2, 512, 256, 512, 1, nullptr, nullptr);
  gemm_bias_act<0><<<dim3(128 / BN, 512 / BM), 256, 0, stream>>>(
      z2, h3, hb3, z3, 512, 128, 256, 1, nullptr, nullptr);
  head_final<<<512, 64, 0, stream>>>(z3, h4, hb4, out);
}

// Round 3
// 1394.842 us; speedup vs baseline: 4.7043x; 4.7043x over previous
//
#include <hip/hip_runtime.h>
#include <cstddef>
#include <cstdint>

// ---------------------------------------------------------------------------
// LogicRecursiveNN — Round 3 == Round 2 resubmit (R2 was an infra timeout).
// fp16 MFMA for the 14 heavy GEMMs (fp32 accum), f32 head. m97 structure:
// 128x128 tile, BK=64, 4 waves, global_load_lds(16), XOR-swizzled LDS
// (linear dest + pre-swizzled source + swizzled read).
// ---------------------------------------------------------------------------

typedef _Float16 f16;
typedef _Float16 f16x8 __attribute__((ext_vector_type(8)));
typedef float f32x4 __attribute__((ext_vector_type(4)));

__device__ __forceinline__ void gll16(const void* g, void* l) {
  __builtin_amdgcn_global_load_lds(
      (const __attribute__((address_space(1))) void*)g,
      (__attribute__((address_space(3))) void*)l, 16, 0, 0);
}

// C[M,N] = act(A[M,K] @ Bt[N,K]^T + bias), A/Bt f16, accum f32.
// ACT: 1=relu, 2=tanh. OUTF32: store float instead of f16.
// M,N multiples of 128; K multiple of 64.
template <int ACT, int OUTF32>
__global__ __launch_bounds__(256) void gemm_f16(
    const f16* __restrict__ A, const f16* __restrict__ Bt,
    const float* __restrict__ bias, void* __restrict__ Cout, int N, int K) {
  __shared__ __align__(16) f16 As[128 * 64];
  __shared__ __align__(16) f16 Bs[128 * 64];
  const int tid = threadIdx.x;
  const int m0 = blockIdx.y * 128;
  const int n0 = blockIdx.x * 128;

  // ---- staging (256 thr cover 32 rows x 8 chunks of 16B per round; 4 rounds)
  // LDS dest is linear (row*128B + chunk*16B); source chunk is pre-swizzled
  // so that a read at cb ^ ((row&7)<<4) returns logical cb.
  const int srow = tid >> 3;                            // 0..31
  const int sk = ((tid & 7) ^ ((tid >> 3) & 7)) << 3;   // f16 elems, 0..56
  const f16* Ag = A + (size_t)(m0 + srow) * K + sk;
  const f16* Bg = Bt + (size_t)(n0 + srow) * K + sk;
  char* Al = (char*)As + (tid >> 6) * 1024;  // wave base; HW adds lane*16
  char* Bl = (char*)Bs + (tid >> 6) * 1024;

  // ---- compute mapping: 4 waves in 2x2, each 64x64 = 4x4 frags of 16x16
  const int l = tid & 63;
  const int wm = tid >> 7;         // 0..1
  const int wn = (tid >> 6) & 1;   // 0..1
  const int q = l & 15;
  const int kg = l >> 4;           // 0..3
  const char* Ar = (const char*)As + (wm * 64 + q) * 128;
  const char* Br = (const char*)Bs + (wn * 64 + q) * 128;
  const int c0 = ((kg << 4) ^ ((q & 7) << 4));  // swizzled byte col, ks=0

  f32x4 acc[4][4] = {};

  for (int k0 = 0; k0 < K; k0 += 64) {
#pragma unroll
    for (int r = 0; r < 4; ++r) {
      gll16(Ag + (size_t)(r * 32) * K + k0, Al + r * 4096);
      gll16(Bg + (size_t)(r * 32) * K + k0, Bl + r * 4096);
    }
    __syncthreads();  // drains vmcnt(0) then barrier
#pragma unroll
    for (int ks = 0; ks < 2; ++ks) {
      const int cb = c0 ^ (ks << 6);
      f16x8 a[4], b[4];
#pragma unroll
      for (int i = 0; i < 4; ++i) a[i] = *(const f16x8*)(Ar + i * 2048 + cb);
#pragma unroll
      for (int j = 0; j < 4; ++j) b[j] = *(const f16x8*)(Br + j * 2048 + cb);
#pragma unroll
      for (int i = 0; i < 4; ++i)
#pragma unroll
        for (int j = 0; j < 4; ++j)
          acc[i][j] = __builtin_amdgcn_mfma_f32_16x16x32_f16(a[i], b[j],
                                                             acc[i][j], 0, 0, 0);
    }
    __syncthreads();
  }

  // ---- epilogue: C row = i*16 + kg*4 + vi, col = j*16 + q (m89 layout)
#pragma unroll
  for (int j = 0; j < 4; ++j) {
    const int col = n0 + wn * 64 + j * 16 + q;
    const float bsv = bias[col];
#pragma unroll
    for (int i = 0; i < 4; ++i) {
      f32x4 v = acc[i][j];
#pragma unroll
      for (int vi = 0; vi < 4; ++vi) {
        const int row = m0 + wm * 64 + i * 16 + kg * 4 + vi;
        float c = v[vi] + bsv;
        if (ACT == 1) c = fmaxf(c, 0.0f);
        if (ACT == 2) c = tanhf(c);
        if (OUTF32)
          ((float*)Cout)[(size_t)row * N + col] = c;
        else
          ((f16*)Cout)[(size_t)row * N + col] = (f16)c;
      }
    }
  }
}

// dst[n][k] = (f16) src[k][n];  K,N multiples of 32
__global__ void transpose_cvt(const float* __restrict__ src,
                              f16* __restrict__ dst, int K, int N) {
  __shared__ f16 tile[32][33];
  const int k0 = blockIdx.x * 32, n0 = blockIdx.y * 32;
  const int tx = threadIdx.x & 31, ty = threadIdx.x >> 5;  // ty 0..7
  for (int r = ty; r < 32; r += 8)
    tile[r][tx] = (f16)src[(size_t)(k0 + r) * N + n0 + tx];
  __syncthreads();
  for (int r = ty; r < 32; r += 8)
    dst[(size_t)(n0 + r) * K + k0 + tx] = tile[tx][r];
}

// X0[j][0:512] = (f16) ent_emb[leaf_idx[j]][0:512], j in [0, 65536)
__global__ void gather_cvt(const int* __restrict__ lidx,
                           const float* __restrict__ emb,
                           f16* __restrict__ X0) {
  const int g = blockIdx.x * 256 + threadIdx.x;  // 8 elems each
  const int row = g >> 6;
  const int e0 = (g & 63) << 3;
  const int ent = lidx[row];
  const float4* s = (const float4*)(emb + ((size_t)ent << 9) + e0);
  float4 v0 = s[0], v1 = s[1];
  f16x8 o;
  o[0] = (f16)v0.x; o[1] = (f16)v0.y; o[2] = (f16)v0.z; o[3] = (f16)v0.w;
  o[4] = (f16)v1.x; o[5] = (f16)v1.y; o[6] = (f16)v1.z; o[7] = (f16)v1.w;
  *(f16x8*)(X0 + ((size_t)row << 9) + e0) = o;
}

// ---- f32 head GEMM (round-1 kernel, gather path removed) -------------------
#define BM 64
#define BN 64
#define BKK 16
__global__ __launch_bounds__(256) void gemm_f32(
    const float* __restrict__ A, const float* __restrict__ W,
    const float* __restrict__ bias, float* __restrict__ C, int N, int K,
    int act) {
  __shared__ float As[BKK][BM + 4];
  __shared__ float Ws[BKK][BN];
  const int tid = threadIdx.x;
  const int m0 = blockIdx.y * BM;
  const int n0 = blockIdx.x * BN;
  const int tm = (tid >> 4) << 2;
  const int tn = (tid & 15) << 2;
  const int lm = tid >> 2;
  const int lk = (tid & 3) << 2;
  const int wk = tid >> 4;
  const int wn = (tid & 15) << 2;
  float acc[4][4] = {};
  for (int k0 = 0; k0 < K; k0 += BKK) {
    float4 av = *(const float4*)(A + (size_t)(m0 + lm) * K + k0 + lk);
    As[lk + 0][lm] = av.x;
    As[lk + 1][lm] = av.y;
    As[lk + 2][lm] = av.z;
    As[lk + 3][lm] = av.w;
    *(float4*)&Ws[wk][wn] = *(const float4*)(W + (size_t)(k0 + wk) * N + n0 + wn);
    __syncthreads();
#pragma unroll
    for (int k = 0; k < BKK; ++k) {
      float4 a = *(const float4*)&As[k][tm];
      float4 w = *(const float4*)&Ws[k][tn];
      acc[0][0] += a.x * w.x; acc[0][1] += a.x * w.y;
      acc[0][2] += a.x * w.z; acc[0][3] += a.x * w.w;
      acc[1][0] += a.y * w.x; acc[1][1] += a.y * w.y;
      acc[1][2] += a.y * w.z; acc[1][3] += a.y * w.w;
      acc[2][0] += a.z * w.x; acc[2][1] += a.z * w.y;
      acc[2][2] += a.z * w.z; acc[2][3] += a.z * w.w;
      acc[3][0] += a.w * w.x; acc[3][1] += a.w * w.y;
      acc[3][2] += a.w * w.z; acc[3][3] += a.w * w.w;
    }
    __syncthreads();
  }
#pragma unroll
  for (int i = 0; i < 4; ++i)
#pragma unroll
    for (int j = 0; j < 4; ++j) {
      float c = acc[i][j] + bias[n0 + tn + j];
      if (act == 1) c = fmaxf(c, 0.0f);
      C[(size_t)(m0 + tm + i) * N + n0 + tn + j] = c;
    }
}

__global__ void build_feat(const float* __restrict__ th,
                           const float* __restrict__ root2,
                           float* __restrict__ feat) {
  int idx = blockIdx.x * 256 + threadIdx.x;  // 512*1536 total
  int b = idx / 1536;
  int c = idx - b * 1536;
  feat[idx] = (c < 512) ? th[c] : root2[(size_t)b * 1024 + (c - 512)];
}

__global__ void head_final(const float* __restrict__ z3,
                           const float* __restrict__ h4,
                           const float* __restrict__ hb4,
                           float* __restrict__ out) {
  int row = blockIdx.x;
  int t = threadIdx.x;  // 64
  float v = z3[(size_t)row * 128 + t] * h4[t] +
            z3[(size_t)row * 128 + 64 + t] * h4[64 + t];
#pragma unroll
  for (int off = 32; off; off >>= 1) v += __shfl_down(v, off);
  if (t == 0) out[row] = 1.0f / (1.0f + expf(-(v + hb4[0])));
}

extern "C" void kernel_launch(void* const* d_in, const int* in_sizes, int n_in,
                              void* d_out, int out_size, void* d_ws,
                              size_t ws_size, hipStream_t stream) {
  const int* leaf_idx = (const int*)d_in[0];
  const float* ent_emb = (const float*)d_in[1];
  const float* th_emb = (const float*)d_in[2];
  const float* w1 = (const float*)d_in[3];
  const float* b1 = (const float*)d_in[4];
  const float* w2 = (const float*)d_in[5];
  const float* b2 = (const float*)d_in[6];
  const float* o1 = (const float*)d_in[7];
  const float* ob1 = (const float*)d_in[8];
  const float* o2 = (const float*)d_in[9];
  const float* ob2 = (const float*)d_in[10];
  const float* h1 = (const float*)d_in[11];
  const float* hb1 = (const float*)d_in[12];
  const float* h2 = (const float*)d_in[13];
  const float* hb2 = (const float*)d_in[14];
  const float* h3 = (const float*)d_in[15];
  const float* hb3 = (const float*)d_in[16];
  const float* h4 = (const float*)d_in[17];
  const float* hb4 = (const float*)d_in[18];
  float* out = (float*)d_out;

  char* p = (char*)d_ws;
  f16* w1t = (f16*)p;  p += (size_t)2048 * 1024 * 2;
  f16* w2t = (f16*)p;  p += (size_t)512 * 2048 * 2;
  f16* o1t = (f16*)p;  p += (size_t)2048 * 512 * 2;
  f16* o2t = (f16*)p;  p += (size_t)512 * 2048 * 2;
  f16* X0  = (f16*)p;  p += (size_t)65536 * 512 * 2;
  f16* bufA = (f16*)p; p += (size_t)32768 * 512 * 2;
  f16* bufB = (f16*)p; p += (size_t)16384 * 512 * 2;
  f16* Hf  = (f16*)p;  p += (size_t)4096 * 2048 * 2;
  float* root2 = (float*)p; p += (size_t)1024 * 512 * 4;
  float* feat = (float*)p;  p += (size_t)512 * 1536 * 4;
  float* z1 = (float*)p;    p += (size_t)512 * 512 * 4;
  float* z2 = (float*)p;    p += (size_t)512 * 256 * 4;
  float* z3 = (float*)p;    p += (size_t)512 * 128 * 4;

  // ---- prep: weight transpose+convert, leaf gather+convert
  transpose_cvt<<<dim3(1024 / 32, 2048 / 32), 256, 0, stream>>>(w1, w1t, 1024, 2048);
  transpose_cvt<<<dim3(2048 / 32, 512 / 32), 256, 0, stream>>>(w2, w2t, 2048, 512);
  transpose_cvt<<<dim3(512 / 32, 2048 / 32), 256, 0, stream>>>(o1, o1t, 512, 2048);
  transpose_cvt<<<dim3(2048 / 32, 512 / 32), 256, 0, stream>>>(o2, o2t, 2048, 512);
  gather_cvt<<<16384, 256, 0, stream>>>(leaf_idx, ent_emb, X0);

  // ---- 6 tree levels, H chunked to 4096 rows
  const f16* inb = X0;
  int pairs = 32;
  for (int level = 0; level < 6; ++level) {
    int M = 1024 * pairs;
    f16* outb = (level & 1) ? bufB : bufA;
    for (int r0 = 0; r0 < M; r0 += 4096) {
      int rows = (M - r0) < 4096 ? (M - r0) : 4096;
      gemm_f16<1, 0><<<dim3(2048 / 128, rows / 128), 256, 0, stream>>>(
          inb + (size_t)r0 * 1024, w1t, b1, Hf, 2048, 1024);
      gemm_f16<1, 0><<<dim3(512 / 128, rows / 128), 256, 0, stream>>>(
          Hf, w2t, b2, outb + (size_t)r0 * 512, 512, 2048);
    }
    inb = outb;
    pairs >>= 1;
  }

  // ---- one2one: relu(root@o1+ob1) -> tanh(..@o2+ob2), root2 in f32
  gemm_f16<1, 0><<<dim3(2048 / 128, 1024 / 128), 256, 0, stream>>>(
      inb, o1t, ob1, Hf, 2048, 512);
  gemm_f16<2, 1><<<dim3(512 / 128, 1024 / 128), 256, 0, stream>>>(
      Hf, o2t, ob2, root2, 512, 2048);

  // ---- head (f32)
  build_feat<<<(512 * 1536) / 256, 256, 0, stream>>>(th_emb, root2, feat);
  gemm_f32<<<dim3(512 / BN, 512 / BM), 256, 0, stream>>>(feat, h1, hb1, z1, 512,
                                                         1536, 1);
  gemm_f32<<<dim3(256 / BN, 512 / BM), 256, 0, stream>>>(z1, h2, hb2, z2, 256,
                                                         512, 1);
  gemm_f32<<<dim3(128 / BN, 512 / BM), 256, 0, stream>>>(z2, h3, hb3, z3, 128,
                                                         256, 1);
  head_final<<<512, 64, 0, stream>>>(z3, h4, hb4, out);
}

// Round 4
// 888.698 us; speedup vs baseline: 7.3835x; 1.5695x over previous
//
#include <hip/hip_runtime.h>
#include <cstddef>
#include <cstdint>

// ---------------------------------------------------------------------------
// LogicRecursiveNN — Round 4: all GEMMs on fp16 MFMA (fp32 accum).
//  - head (h1/h2/h3) moved from f32 VALU to f16 MFMA   (~230us -> ~15us)
//  - leaf gather fused into level-0 GEMM1 staging (per-lane global src of
//    global_load_lds), X0 eliminated
//  - CHUNK 16384 (fewer dispatches, better N=512 GEMM2 grid fill)
// m97 GEMM structure kept verbatim from R3 (passed): 128x128 tile, BK=64,
// 4 waves, global_load_lds(16), both-sides XOR-swizzled LDS.
// ---------------------------------------------------------------------------

typedef _Float16 f16;
typedef _Float16 f16x8 __attribute__((ext_vector_type(8)));
typedef float f32x4 __attribute__((ext_vector_type(4)));

__device__ __forceinline__ void gll16(const void* g, void* l) {
  __builtin_amdgcn_global_load_lds(
      (const __attribute__((address_space(1))) void*)g,
      (__attribute__((address_space(3))) void*)l, 16, 0, 0);
}

// C[M,N] = act(A[M,K] @ Bt[N,K]^T + bias), A/Bt f16, accum f32.
// ACT: 1=relu, 2=tanh. OUTF32: store float. GATHER: A row r is
// entf[lidx[2r + (k>>9)]][k&511] (level-0 leaf-pair gather, K==1024).
// M,N multiples of 128; K multiple of 64 (and GATHER requires K==1024).
template <int ACT, int OUTF32, int GATHER>
__global__ __launch_bounds__(256) void gemm_f16(
    const f16* __restrict__ A, const f16* __restrict__ Bt,
    const float* __restrict__ bias, void* __restrict__ Cout, int N, int K,
    const int* __restrict__ lidx, const f16* __restrict__ entf) {
  __shared__ __align__(16) f16 As[128 * 64];
  __shared__ __align__(16) f16 Bs[128 * 64];
  const int tid = threadIdx.x;
  const int m0 = blockIdx.y * 128;
  const int n0 = blockIdx.x * 128;

  // ---- staging: 256 thr cover 32 rows x 8 chunks of 16B per round; 4 rounds.
  // LDS dest linear (row*128B + chunk*16B == wave_base + lane*16); source
  // k-chunk pre-swizzled so a read at cb ^ ((row&7)<<4) returns logical cb.
  const int srow = tid >> 3;                           // 0..31
  const int sk = ((tid & 7) ^ ((tid >> 3) & 7)) << 3;  // f16 elems 0..56
  const f16* Ag = A + (size_t)(m0 + srow) * K + sk;
  const f16* Bg = Bt + (size_t)(n0 + srow) * K + sk;
  char* Al = (char*)As + (tid >> 6) * 1024;  // wave base; HW adds lane*16
  char* Bl = (char*)Bs + (tid >> 6) * 1024;

  int ent0[4], ent1[4];
  if (GATHER) {
#pragma unroll
    for (int r = 0; r < 4; ++r) {
      const int row2 = (m0 + srow + 32 * r) << 1;
      ent0[r] = lidx[row2];
      ent1[r] = lidx[row2 + 1];
    }
  }

  // ---- compute mapping: 4 waves 2x2, each 64x64 = 4x4 frags of 16x16x32
  const int l = tid & 63;
  const int wm = tid >> 7;        // 0..1
  const int wn = (tid >> 6) & 1;  // 0..1
  const int q = l & 15;
  const int kg = l >> 4;          // 0..3
  const char* Ar = (const char*)As + (wm * 64 + q) * 128;
  const char* Br = (const char*)Bs + (wn * 64 + q) * 128;
  const int c0 = ((kg << 4) ^ ((q & 7) << 4));  // swizzled byte col at ks=0

  f32x4 acc[4][4] = {};

  for (int k0 = 0; k0 < K; k0 += 64) {
    if (GATHER) {
      const int h = k0 >> 9;
      const int kk = (k0 & 511) + sk;
#pragma unroll
      for (int r = 0; r < 4; ++r) {
        const int e = h ? ent1[r] : ent0[r];
        gll16(entf + ((size_t)e << 9) + kk, Al + r * 4096);
        gll16(Bg + (size_t)(r * 32) * K + k0, Bl + r * 4096);
      }
    } else {
#pragma unroll
      for (int r = 0; r < 4; ++r) {
        gll16(Ag + (size_t)(r * 32) * K + k0, Al + r * 4096);
        gll16(Bg + (size_t)(r * 32) * K + k0, Bl + r * 4096);
      }
    }
    __syncthreads();  // drains vmcnt(0) then barrier
#pragma unroll
    for (int ks = 0; ks < 2; ++ks) {
      const int cb = c0 ^ (ks << 6);
      f16x8 a[4], b[4];
#pragma unroll
      for (int i = 0; i < 4; ++i) a[i] = *(const f16x8*)(Ar + i * 2048 + cb);
#pragma unroll
      for (int j = 0; j < 4; ++j) b[j] = *(const f16x8*)(Br + j * 2048 + cb);
#pragma unroll
      for (int i = 0; i < 4; ++i)
#pragma unroll
        for (int j = 0; j < 4; ++j)
          acc[i][j] = __builtin_amdgcn_mfma_f32_16x16x32_f16(a[i], b[j],
                                                             acc[i][j], 0, 0, 0);
    }
    __syncthreads();
  }

  // ---- epilogue: C row = i*16 + kg*4 + vi, col = j*16 + q (m89 layout)
#pragma unroll
  for (int j = 0; j < 4; ++j) {
    const int col = n0 + wn * 64 + j * 16 + q;
    const float bsv = bias[col];
#pragma unroll
    for (int i = 0; i < 4; ++i) {
      f32x4 v = acc[i][j];
#pragma unroll
      for (int vi = 0; vi < 4; ++vi) {
        const int row = m0 + wm * 64 + i * 16 + kg * 4 + vi;
        float c = v[vi] + bsv;
        if (ACT == 1) c = fmaxf(c, 0.0f);
        if (ACT == 2) c = tanhf(c);
        if (OUTF32)
          ((float*)Cout)[(size_t)row * N + col] = c;
        else
          ((f16*)Cout)[(size_t)row * N + col] = (f16)c;
      }
    }
  }
}

// dst[n][k] = (f16) src[k][n];  K,N multiples of 32
__global__ void transpose_cvt(const float* __restrict__ src,
                              f16* __restrict__ dst, int K, int N) {
  __shared__ f16 tile[32][33];
  const int k0 = blockIdx.x * 32, n0 = blockIdx.y * 32;
  const int tx = threadIdx.x & 31, ty = threadIdx.x >> 5;  // ty 0..7
  for (int r = ty; r < 32; r += 8)
    tile[r][tx] = (f16)src[(size_t)(k0 + r) * N + n0 + tx];
  __syncthreads();
  for (int r = ty; r < 32; r += 8)
    dst[(size_t)(n0 + r) * K + k0 + tx] = tile[tx][r];
}

// f32 -> f16 elementwise, 8 per thread (total multiple of 2048)
__global__ void cvt_f16(const float* __restrict__ src, f16* __restrict__ dst) {
  const int g = blockIdx.x * 256 + threadIdx.x;
  const float4* s = (const float4*)(src + (size_t)g * 8);
  float4 v0 = s[0], v1 = s[1];
  f16x8 o;
  o[0] = (f16)v0.x; o[1] = (f16)v0.y; o[2] = (f16)v0.z; o[3] = (f16)v0.w;
  o[4] = (f16)v1.x; o[5] = (f16)v1.y; o[6] = (f16)v1.z; o[7] = (f16)v1.w;
  *(f16x8*)(dst + (size_t)g * 8) = o;
}

// featf16[b][0:512] = (f16) th_emb; featf16[b][512:1536] = rootf16[b*1024+..]
__global__ void build_feat_h(const float* __restrict__ th,
                             const f16* __restrict__ root,
                             f16* __restrict__ feat) {
  int idx = blockIdx.x * 256 + threadIdx.x;  // 512*1536 total
  int b = idx / 1536;
  int c = idx - b * 1536;
  feat[idx] = (c < 512) ? (f16)th[c] : root[(size_t)b * 1024 + (c - 512)];
}

// out[row] = sigmoid(dot(z3[row, 0:128], h4) + hb4)
__global__ void head_final(const float* __restrict__ z3,
                           const float* __restrict__ h4,
                           const float* __restrict__ hb4,
                           float* __restrict__ out) {
  int row = blockIdx.x;
  int t = threadIdx.x;  // 64
  float v = z3[(size_t)row * 128 + t] * h4[t] +
            z3[(size_t)row * 128 + 64 + t] * h4[64 + t];
#pragma unroll
  for (int off = 32; off; off >>= 1) v += __shfl_down(v, off);
  if (t == 0) out[row] = 1.0f / (1.0f + expf(-(v + hb4[0])));
}

extern "C" void kernel_launch(void* const* d_in, const int* in_sizes, int n_in,
                              void* d_out, int out_size, void* d_ws,
                              size_t ws_size, hipStream_t stream) {
  const int* leaf_idx = (const int*)d_in[0];
  const float* ent_emb = (const float*)d_in[1];
  const float* th_emb = (const float*)d_in[2];
  const float* w1 = (const float*)d_in[3];
  const float* b1 = (const float*)d_in[4];
  const float* w2 = (const float*)d_in[5];
  const float* b2 = (const float*)d_in[6];
  const float* o1 = (const float*)d_in[7];
  const float* ob1 = (const float*)d_in[8];
  const float* o2 = (const float*)d_in[9];
  const float* ob2 = (const float*)d_in[10];
  const float* h1 = (const float*)d_in[11];
  const float* hb1 = (const float*)d_in[12];
  const float* h2 = (const float*)d_in[13];
  const float* hb2 = (const float*)d_in[14];
  const float* h3 = (const float*)d_in[15];
  const float* hb3 = (const float*)d_in[16];
  const float* h4 = (const float*)d_in[17];
  const float* hb4 = (const float*)d_in[18];
  float* out = (float*)d_out;

  char* p = (char*)d_ws;
  f16* w1t = (f16*)p;  p += (size_t)2048 * 1024 * 2;   // 4 MB
  f16* w2t = (f16*)p;  p += (size_t)512 * 2048 * 2;    // 2 MB
  f16* o1t = (f16*)p;  p += (size_t)2048 * 512 * 2;    // 2 MB
  f16* o2t = (f16*)p;  p += (size_t)512 * 2048 * 2;    // 2 MB
  f16* h1t = (f16*)p;  p += (size_t)512 * 1536 * 2;    // 1.5 MB
  f16* h2t = (f16*)p;  p += (size_t)256 * 512 * 2;
  f16* h3t = (f16*)p;  p += (size_t)128 * 256 * 2;
  f16* entf = (f16*)p; p += (size_t)2000 * 512 * 2;    // 2 MB
  f16* bufA = (f16*)p; p += (size_t)32768 * 512 * 2;   // 32 MB
  f16* bufB = (f16*)p; p += (size_t)16384 * 512 * 2;   // 16 MB
  f16* Hf   = (f16*)p; p += (size_t)16384 * 2048 * 2;  // 64 MB
  f16* featf = (f16*)p; p += (size_t)512 * 1536 * 2;
  f16* z1h  = (f16*)p; p += (size_t)512 * 512 * 2;
  f16* z2h  = (f16*)p; p += (size_t)512 * 256 * 2;
  float* z3 = (float*)p; p += (size_t)512 * 128 * 4;
  // total ~= 130 MB (<= 143 MB proven in R3)

  // ---- prep: weight transposes + ent_emb f16 copy
  transpose_cvt<<<dim3(1024 / 32, 2048 / 32), 256, 0, stream>>>(w1, w1t, 1024, 2048);
  transpose_cvt<<<dim3(2048 / 32, 512 / 32), 256, 0, stream>>>(w2, w2t, 2048, 512);
  transpose_cvt<<<dim3(512 / 32, 2048 / 32), 256, 0, stream>>>(o1, o1t, 512, 2048);
  transpose_cvt<<<dim3(2048 / 32, 512 / 32), 256, 0, stream>>>(o2, o2t, 2048, 512);
  transpose_cvt<<<dim3(1536 / 32, 512 / 32), 256, 0, stream>>>(h1, h1t, 1536, 512);
  transpose_cvt<<<dim3(512 / 32, 256 / 32), 256, 0, stream>>>(h2, h2t, 512, 256);
  transpose_cvt<<<dim3(256 / 32, 128 / 32), 256, 0, stream>>>(h3, h3t, 256, 128);
  cvt_f16<<<(2000 * 512) / 2048, 256, 0, stream>>>(ent_emb, entf);

  // ---- 6 tree levels (two2one), H chunked to 16384 rows
  const f16* inb = nullptr;
  int pairs = 32;
  const int CHUNK = 16384;
  for (int level = 0; level < 6; ++level) {
    int M = 1024 * pairs;
    f16* outb = (level & 1) ? bufB : bufA;
    for (int r0 = 0; r0 < M; r0 += CHUNK) {
      int rows = (M - r0) < CHUNK ? (M - r0) : CHUNK;
      if (level == 0) {
        gemm_f16<1, 0, 1><<<dim3(2048 / 128, rows / 128), 256, 0, stream>>>(
            nullptr, w1t, b1, Hf, 2048, 1024, leaf_idx + (size_t)2 * r0, entf);
      } else {
        gemm_f16<1, 0, 0><<<dim3(2048 / 128, rows / 128), 256, 0, stream>>>(
            inb + (size_t)r0 * 1024, w1t, b1, Hf, 2048, 1024, nullptr, nullptr);
      }
      gemm_f16<1, 0, 0><<<dim3(512 / 128, rows / 128), 256, 0, stream>>>(
          Hf, w2t, b2, outb + (size_t)r0 * 512, 512, 2048, nullptr, nullptr);
    }
    inb = outb;
    pairs >>= 1;
  }

  // ---- one2one: relu(root@o1+ob1) -> tanh(..@o2+ob2) -> f16 root [1024,512]
  gemm_f16<1, 0, 0><<<dim3(2048 / 128, 1024 / 128), 256, 0, stream>>>(
      inb, o1t, ob1, Hf, 2048, 512, nullptr, nullptr);
  f16* rootf = bufA;  // bufA free at this point (last tree output was bufB)
  gemm_f16<2, 0, 0><<<dim3(512 / 128, 1024 / 128), 256, 0, stream>>>(
      Hf, o2t, ob2, rootf, 512, 2048, nullptr, nullptr);

  // ---- head (f16 MFMA)
  build_feat_h<<<(512 * 1536) / 256, 256, 0, stream>>>(th_emb, rootf, featf);
  gemm_f16<1, 0, 0><<<dim3(512 / 128, 512 / 128), 256, 0, stream>>>(
      featf, h1t, hb1, z1h, 512, 1536, nullptr, nullptr);
  gemm_f16<1, 0, 0><<<dim3(256 / 128, 512 / 128), 256, 0, stream>>>(
      z1h, h2t, hb2, z2h, 256, 512, nullptr, nullptr);
  gemm_f16<1, 1, 0><<<dim3(128 / 128, 512 / 128), 256, 0, stream>>>(
      z2h, h3t, hb3, z3, 128, 256, nullptr, nullptr);
  head_final<<<512, 64, 0, stream>>>(z3, h4, hb4, out);
}